// Round 2
// baseline (586.401 us; speedup 1.0000x reference)
//
#include <hip/hip_runtime.h>

// Causal single-head attention, B=8, N=2048, D=1024, fp32 in/out, bf16 MFMA compute.
//
// Pipeline (all on `stream`):
//   1. cast_f32_bf16:      x (fp32) -> xb (bf16)
//   2. transpose_cast_w:   Wq/Wk/Wv (fp32 KxN) -> WT (bf16 NxK)  [B^T layout for GEMM]
//   3. gemm_bt<0>: Q = xb·Wq   (bf16 out, row-major)
//      gemm_bt<0>: K = xb·Wk
//      gemm_bt<1>: Vt = (xb·Wv)^T per batch  (bf16, [D][N])
//   4. per 2-batch chunk (keeps S buffer at 33.5 MB; total ws 166 MiB < 256 MiB):
//      gemm_bt<2>: S = (Q·K^T)·scale  (fp32), lower-triangular 128x128 tiles only
//      softmax_rows: P = softmax(S) written bf16 IN PLACE over S rows (zeros past diag)
//      gemm_bt<3>: out = P·V  via Vt, fp32, K-loop causally limited

typedef unsigned short u16;
typedef __bf16 bf16x8 __attribute__((ext_vector_type(8)));
typedef float f32x4 __attribute__((ext_vector_type(4)));
typedef unsigned short u16x8 __attribute__((ext_vector_type(8)));

static constexpr int BATCH = 8;
static constexpr int SEQ = 2048;
static constexpr int DIM = 1024;
static constexpr int CHUNK_B = 2;  // batches per S chunk

static constexpr size_t SZ_XB = (size_t)BATCH * SEQ * DIM * 2;   // 32 MiB
static constexpr size_t SZ_W  = (size_t)DIM * DIM * 2;           // 2 MiB
static constexpr size_t OFF_XB  = 0;
static constexpr size_t OFF_WQT = OFF_XB + SZ_XB;
static constexpr size_t OFF_WKT = OFF_WQT + SZ_W;
static constexpr size_t OFF_WVT = OFF_WKT + SZ_W;
static constexpr size_t OFF_Q   = OFF_WVT + SZ_W;
static constexpr size_t OFF_K   = OFF_Q + SZ_XB;
static constexpr size_t OFF_VT  = OFF_K + SZ_XB;
static constexpr size_t OFF_S   = OFF_VT + SZ_XB;  // CHUNK_B*SEQ*SEQ*4 = 33.5 MB
// total = 140,509,184 + 33,554,432 = 174,063,616 B ≈ 166 MiB

__device__ __forceinline__ u16 f2b(float f) {
  // round-to-nearest-even fp32 -> bf16 (finite inputs only)
  unsigned u = __builtin_bit_cast(unsigned, f);
  u += 0x7fffu + ((u >> 16) & 1u);
  return (u16)(u >> 16);
}

__device__ __forceinline__ void gload16(const u16* g, u16* l) {
  // async global->LDS, 16B per lane. Proper addrspacecast (NOT integer round-trip:
  // generic LDS ptr holds the flat-aperture address; truncating it is UB).
  __builtin_amdgcn_global_load_lds((__attribute__((address_space(1))) void*)g,
                                   (__attribute__((address_space(3))) void*)l, 16, 0, 0);
}

__global__ __launch_bounds__(256) void cast_f32_bf16(const float* __restrict__ in,
                                                     u16* __restrict__ out) {
  const size_t i = ((size_t)blockIdx.x * 256 + threadIdx.x) * 8;
  float4 a = *(const float4*)(in + i);
  float4 b = *(const float4*)(in + i + 4);
  u16x8 o;
  o[0] = f2b(a.x); o[1] = f2b(a.y); o[2] = f2b(a.z); o[3] = f2b(a.w);
  o[4] = f2b(b.x); o[5] = f2b(b.y); o[6] = f2b(b.z); o[7] = f2b(b.w);
  *reinterpret_cast<u16x8*>(out + i) = o;
}

// WT[n][k] = W[k][n], fp32 -> bf16. block (32,8), grid (32,32)
__global__ __launch_bounds__(256) void transpose_cast_w(const float* __restrict__ W,
                                                        u16* __restrict__ WT) {
  __shared__ float t[32][33];
  const int k0 = blockIdx.x * 32, n0 = blockIdx.y * 32;
  const int tx = threadIdx.x, ty = threadIdx.y;
#pragma unroll
  for (int dy = 0; dy < 32; dy += 8)
    t[ty + dy][tx] = W[(size_t)(k0 + ty + dy) * DIM + n0 + tx];
  __syncthreads();
#pragma unroll
  for (int dy = 0; dy < 32; dy += 8)
    WT[(size_t)(n0 + ty + dy) * DIM + k0 + tx] = f2b(t[tx][ty + dy]);
}

// C = A(bf16, MxK row-major) * B(bf16) with B given transposed: Bt (N x K row-major).
// 128x128 tile / 256 threads = 4 waves, each wave 64x64 = 4x4 mfma_f32_16x16x32_bf16.
// MODE 0: C bf16 row-major (ldc, batch stride sC)
// MODE 1: C bf16 transposed per batch: C[b][col][n] with b=row>>11, n=row&2047 (Vt build)
// MODE 2: C fp32 = acc*scale, skip tiles with bx>by (causal lower-triangular only)
// MODE 3: C fp32, K-loop limited to (by+1)*128 (P has zeros past the diagonal)
template <int MODE>
__global__ __launch_bounds__(256, 2) void gemm_bt(
    const u16* __restrict__ A, size_t sA, int lda,
    const u16* __restrict__ Bt, size_t sB, int ldb,
    void* __restrict__ C, size_t sC, int ldc,
    int M, int Ncols, int Kdim, float scale) {
  const int bx = blockIdx.x, by = blockIdx.y, bz = blockIdx.z;
  if (MODE == 2 && bx > by) return;
  const u16* Ab = A + (size_t)bz * sA;
  const u16* Bb = Bt + (size_t)bz * sB;
  const int rowTile = by * 128, colTile = bx * 128;
  int kmax = Kdim;
  if (MODE == 3) {
    int km = (by + 1) * 128;
    if (km < kmax) kmax = km;
  }

  __shared__ u16 As[128 * 32];
  __shared__ u16 Bs[128 * 32];

  const int tid = threadIdx.x;
  const int w = tid >> 6, l = tid & 63;
  const int wr = (w >> 1) * 64, wc = (w & 1) * 64;  // wave's 64x64 quadrant
  const int lr = l & 15, quad = l >> 4;

  f32x4 acc[4][4];
#pragma unroll
  for (int i = 0; i < 4; ++i)
#pragma unroll
    for (int j = 0; j < 4; ++j) acc[i][j] = (f32x4){0.f, 0.f, 0.f, 0.f};

  // staging: each wave fills 16 consecutive rows (32 bf16 each) per issue; 2 issues each for A,B
  const int srow = w * 16 + (l >> 2);
  const int scol = (l & 3) * 8;
  const u16* gA0 = Ab + (size_t)(rowTile + srow) * lda + scol;
  const u16* gA1 = gA0 + (size_t)64 * lda;
  const u16* gB0 = Bb + (size_t)(colTile + srow) * ldb + scol;
  const u16* gB1 = gB0 + (size_t)64 * ldb;
  u16* lA0 = &As[(w * 16) * 32];
  u16* lA1 = &As[(64 + w * 16) * 32];
  u16* lB0 = &Bs[(w * 16) * 32];
  u16* lB1 = &Bs[(64 + w * 16) * 32];

  for (int k0 = 0; k0 < kmax; k0 += 32) {
    __syncthreads();  // previous iter's compute done before overwrite
    gload16(gA0 + k0, lA0);
    gload16(gA1 + k0, lA1);
    gload16(gB0 + k0, lB0);
    gload16(gB1 + k0, lB1);
    __syncthreads();  // drains vmcnt (global_load_lds) + lds visibility
    bf16x8 af[4], bfr[4];
#pragma unroll
    for (int mi = 0; mi < 4; ++mi)
      af[mi] = *reinterpret_cast<const bf16x8*>(&As[(wr + mi * 16 + lr) * 32 + quad * 8]);
#pragma unroll
    for (int ni = 0; ni < 4; ++ni)
      bfr[ni] = *reinterpret_cast<const bf16x8*>(&Bs[(wc + ni * 16 + lr) * 32 + quad * 8]);
#pragma unroll
    for (int mi = 0; mi < 4; ++mi)
#pragma unroll
      for (int ni = 0; ni < 4; ++ni)
        acc[mi][ni] =
            __builtin_amdgcn_mfma_f32_16x16x32_bf16(af[mi], bfr[ni], acc[mi][ni], 0, 0, 0);
  }

  // C/D layout: col = lane&15, row = (lane>>4)*4 + reg  [m89-verified]
  const int orow0 = rowTile + wr + quad * 4;
  const int ocol0 = colTile + wc + lr;
#pragma unroll
  for (int mi = 0; mi < 4; ++mi) {
#pragma unroll
    for (int ni = 0; ni < 4; ++ni) {
      const int colg = ocol0 + ni * 16;
#pragma unroll
      for (int r = 0; r < 4; ++r) {
        const int rowg = orow0 + mi * 16 + r;
        const float v = acc[mi][ni][r];
        if (MODE == 0) {
          ((u16*)C)[(size_t)bz * sC + (size_t)rowg * ldc + colg] = f2b(v);
        } else if (MODE == 1) {
          const int bb = rowg >> 11, nn = rowg & (SEQ - 1);
          ((u16*)C)[(size_t)bb * sC + (size_t)colg * ldc + nn] = f2b(v);
        } else if (MODE == 2) {
          ((float*)C)[(size_t)bz * sC + (size_t)rowg * ldc + colg] = v * scale;
        } else {
          ((float*)C)[(size_t)bz * sC + (size_t)rowg * ldc + colg] = v;
        }
      }
    }
  }
}

// One block per row. Reads fp32 scaled scores S[row][0..2047] (only 0..n valid),
// writes bf16 P in place over the row start (zeros for c>n). LDS staging makes the
// in-place fp32->bf16 overwrite race-free. n = row & 2047 (rows are per-batch).
__global__ __launch_bounds__(256) void softmax_rows(float* __restrict__ S) {
  const int row = blockIdx.x;
  const int n = row & (SEQ - 1);
  float* Srow = S + (size_t)row * SEQ;
  __shared__ float buf[SEQ];
  __shared__ float red[8];
  const int tid = threadIdx.x;
  float4 v0 = ((const float4*)Srow)[tid * 2 + 0];
  float4 v1 = ((const float4*)Srow)[tid * 2 + 1];
  ((float4*)buf)[tid * 2 + 0] = v0;
  ((float4*)buf)[tid * 2 + 1] = v1;
  __syncthreads();
  const int base = tid * 8;
  float m = -3.0e38f;
#pragma unroll
  for (int j = 0; j < 8; ++j) {
    int c = base + j;
    float s = buf[c];
    m = (c <= n && s > m) ? s : m;
  }
  for (int off = 32; off > 0; off >>= 1) m = fmaxf(m, __shfl_down(m, off));
  if ((tid & 63) == 0) red[tid >> 6] = m;
  __syncthreads();
  m = fmaxf(fmaxf(red[0], red[1]), fmaxf(red[2], red[3]));
  float e[8];
  float lsum = 0.f;
#pragma unroll
  for (int j = 0; j < 8; ++j) {
    int c = base + j;
    float ev = (c <= n) ? __expf(buf[c] - m) : 0.f;
    e[j] = ev;
    lsum += ev;
  }
  for (int off = 32; off > 0; off >>= 1) lsum += __shfl_down(lsum, off);
  if ((tid & 63) == 0) red[4 + (tid >> 6)] = lsum;
  __syncthreads();
  lsum = red[4] + red[5] + red[6] + red[7];
  const float inv = 1.f / lsum;
  u16x8 o;
#pragma unroll
  for (int j = 0; j < 8; ++j) o[j] = f2b(e[j] * inv);
  *reinterpret_cast<u16x8*>(((u16*)Srow) + base) = o;
}

extern "C" void kernel_launch(void* const* d_in, const int* in_sizes, int n_in,
                              void* d_out, int out_size, void* d_ws, size_t ws_size,
                              hipStream_t stream) {
  const float* x = (const float*)d_in[0];
  const float* Wq = (const float*)d_in[1];
  const float* Wk = (const float*)d_in[2];
  const float* Wv = (const float*)d_in[3];
  float* out = (float*)d_out;
  char* ws = (char*)d_ws;

  u16* xb = (u16*)(ws + OFF_XB);
  u16* wqT = (u16*)(ws + OFF_WQT);
  u16* wkT = (u16*)(ws + OFF_WKT);
  u16* wvT = (u16*)(ws + OFF_WVT);
  u16* qb = (u16*)(ws + OFF_Q);
  u16* kb = (u16*)(ws + OFF_K);
  u16* vt = (u16*)(ws + OFF_VT);
  float* S = (float*)(ws + OFF_S);

  const int total = BATCH * SEQ * DIM;  // 16,777,216
  cast_f32_bf16<<<total / (256 * 8), 256, 0, stream>>>(x, xb);
  transpose_cast_w<<<dim3(32, 32), dim3(32, 8), 0, stream>>>(Wq, wqT);
  transpose_cast_w<<<dim3(32, 32), dim3(32, 8), 0, stream>>>(Wk, wkT);
  transpose_cast_w<<<dim3(32, 32), dim3(32, 8), 0, stream>>>(Wv, wvT);

  // Q = xb·Wq, K = xb·Wk  (M=16384, N=1024, K=1024)
  gemm_bt<0><<<dim3(8, 128, 1), 256, 0, stream>>>(xb, 0, DIM, wqT, 0, DIM, qb, 0, DIM,
                                                  BATCH * SEQ, DIM, DIM, 1.f);
  gemm_bt<0><<<dim3(8, 128, 1), 256, 0, stream>>>(xb, 0, DIM, wkT, 0, DIM, kb, 0, DIM,
                                                  BATCH * SEQ, DIM, DIM, 1.f);
  // Vt[b][d][n] = (xb·Wv)[b*2048+n][d]
  gemm_bt<1><<<dim3(8, 128, 1), 256, 0, stream>>>(xb, 0, DIM, wvT, 0, DIM, vt,
                                                  (size_t)DIM * SEQ, SEQ, BATCH * SEQ, DIM,
                                                  DIM, 1.f);

  // Attention phase, chunked over batches to bound the S buffer.
  for (int c = 0; c < BATCH / CHUNK_B; ++c) {
    const u16* qc = qb + (size_t)c * CHUNK_B * SEQ * DIM;
    const u16* kc = kb + (size_t)c * CHUNK_B * SEQ * DIM;
    const u16* vc = vt + (size_t)c * CHUNK_B * DIM * SEQ;
    float* oc = out + (size_t)c * CHUNK_B * SEQ * DIM;
    // S = (Q·K^T)*scale per batch, lower-triangular tiles only
    gemm_bt<2><<<dim3(16, 16, CHUNK_B), 256, 0, stream>>>(
        qc, (size_t)SEQ * DIM, DIM, kc, (size_t)SEQ * DIM, DIM, S, (size_t)SEQ * SEQ, SEQ,
        SEQ, SEQ, DIM, 0.03125f);
    softmax_rows<<<CHUNK_B * SEQ, 256, 0, stream>>>(S);
    // out = P·V via Vt; P is bf16 rows of length 2048 with leading dim 4096 (in-place over S)
    gemm_bt<3><<<dim3(8, 16, CHUNK_B), 256, 0, stream>>>(
        (const u16*)S, (size_t)SEQ * (2 * SEQ), 2 * SEQ, vc, (size_t)DIM * SEQ, SEQ, oc,
        (size_t)SEQ * DIM, DIM, SEQ, DIM, SEQ, 1.f);
  }
}